// Round 1
// baseline (593.803 us; speedup 1.0000x reference)
//
#include <hip/hip_runtime.h>
#include <math.h>

#define TWO_G 19.6f   // 2*9.8, matches jnp's folded 2.0*G constant

__device__ __forceinline__ float flow_q(float th, float d, float a) {
    // matches reference: theta * sqrt(2*G*h) * area, left-associated
    return th * sqrtf(TWO_G * d) * a;
}

// ---------------- Layer 0: single head bucket, 1024 spigots. One wave. ----------------
__global__ __launch_bounds__(64)
void layer0_kernel(const float* __restrict__ H0p, const float* __restrict__ S0,
                   const float* __restrict__ theta0, const float* __restrict__ precip,
                   float* __restrict__ out, float* __restrict__ bufA, float* __restrict__ bufB)
{
    const int lane = threadIdx.x;
    const float H  = H0p[0];
    const float pl = precip[0] * 0.0625f;          // precip / 16 (exact)
    const float pb = pl * (1.0f / 1024.0f);        // / 1024 (exact)

    const float2* S2 = (const float2*)S0;

    float2 sv[16];
#pragma unroll
    for (int c = 0; c < 16; ++c) sv[c] = S2[c * 64 + lane];

    // spigot 0 sees H + inflow; carry immediately becomes H - 0.5*cum
    float h0 = __shfl(sv[0].x, 0);
    float a0 = __shfl(sv[0].y, 0);
    float d0 = (H + pl) - h0;
    float q0 = 0.0f;
    if (d0 > 0.0f) q0 = flow_q(theta0[0], d0, a0);
    float cum = q0;
    float u   = H - 0.5f * cum;
    if (lane == 0) bufA[0] = q0 + pb;

#pragma unroll
    for (int c = 0; c < 16; ++c) {
        int i = c * 64 + lane;
        float2 s = sv[c];
        bufB[i] = pb;                               // init next-layer accumulator
        unsigned long long avail = (c == 0) ? ~1ull : ~0ull;   // spigot 0 already done
        unsigned long long cand  = __ballot(s.x < u) & avail;
        float th = 0.0f, qmine = 0.0f;
        if (cand) {
            if ((cand >> lane) & 1ull) th = theta0[i];   // theta only for candidates
            while (cand) {
                int j = __builtin_ctzll(cand);
                float hj  = __shfl(s.x, j);
                float aj  = __shfl(s.y, j);
                float thj = __shfl(th, j);
                float d = u - hj;                    // > 0 by ballot
                float q = flow_q(thj, d, aj);
                cum += q;
                u = H - 0.5f * cum;
                if (lane == j) qmine = q;
                if (j >= 63) break;
                avail &= (~0ull << (j + 1));
                cand = __ballot(s.x < u) & avail;    // u decreased: subset of old cand
            }
        }
        if (i > 0) bufA[i] = qmine + pb;             // inflow to layer-1 bucket i
    }
    if (lane == 0) out[0] = (H - cum) + pl;          // H0_new
}

// ---------------- Mid layers: 1024 buckets, one wave per bucket. ----------------
__global__ __launch_bounds__(256)
void mid_kernel(const float* __restrict__ Hl, const float* __restrict__ Sl,
                const float* __restrict__ thl, float* __restrict__ cur,
                float* __restrict__ nxt, float* __restrict__ outl,
                const float* __restrict__ precip)
{
    const int lane = threadIdx.x & 63;
    const int b    = blockIdx.x * 4 + (threadIdx.x >> 6);
    const float pb = precip[0] * (0.0625f / 1024.0f);   // exact: 2^-14 * precip

    const float H      = Hl[b];
    const float inflow = cur[b];
    if (lane == 0) cur[b] = pb;    // self-reset: this slot is the accumulator 2 layers later

    const float2* S2     = (const float2*)Sl + (size_t)b * 1024;
    const float*  thrw   = thl + (size_t)b * 1024;

    float2 sv[16];
#pragma unroll
    for (int c = 0; c < 16; ++c) sv[c] = S2[c * 64 + lane];

    float h0 = __shfl(sv[0].x, 0);
    float a0 = __shfl(sv[0].y, 0);
    float d0 = (H + inflow) - h0;
    float q0 = 0.0f;
    if (d0 > 0.0f) q0 = flow_q(thrw[0], d0, a0);
    float cum = q0;
    float u   = H - 0.5f * cum;
    if (lane == 0 && q0 > 0.0f) atomicAdd(&nxt[0], q0);

#pragma unroll
    for (int c = 0; c < 16; ++c) {
        int i = c * 64 + lane;
        float2 s = sv[c];
        unsigned long long avail = (c == 0) ? ~1ull : ~0ull;
        unsigned long long cand  = __ballot(s.x < u) & avail;
        float th = 0.0f, qmine = 0.0f;
        if (cand) {
            if ((cand >> lane) & 1ull) th = thrw[i];
            while (cand) {
                int j = __builtin_ctzll(cand);
                float hj  = __shfl(s.x, j);
                float aj  = __shfl(s.y, j);
                float thj = __shfl(th, j);
                float d = u - hj;
                float q = flow_q(thj, d, aj);
                cum += q;
                u = H - 0.5f * cum;
                if (lane == j) qmine = q;
                if (j >= 63) break;
                avail &= (~0ull << (j + 1));
                cand = __ballot(s.x < u) & avail;
            }
            if (qmine > 0.0f) atomicAdd(&nxt[i], qmine);  // coalesced-ish, sparse
        }
    }
    if (lane == 0) outl[b] = (H - cum) + inflow;          // H_mid_new[l][b]
}

// ---------------- Last layer: 1024 buckets, 1 spigot each. ----------------
__global__ __launch_bounds__(256)
void last_kernel(const float* __restrict__ Hlast, const float* __restrict__ Slast,
                 const float* __restrict__ thlast, const float* __restrict__ cur,
                 float* __restrict__ out)
{
    int b = blockIdx.x * 256 + threadIdx.x;
    float H      = Hlast[b];
    float inflow = cur[b];
    float2 s = ((const float2*)Slast)[b];
    float d = (H + inflow) - s.x;
    float q = 0.0f;
    if (d > 0.0f) q = thlast[b] * sqrtf(TWO_G * d) * s.y;
    out[1 + 14 * 1024 + b]        = (H - q) + inflow;   // H_last_new
    out[1 + 14 * 1024 + 1024 + b] = q;                  // q_last
}

extern "C" void kernel_launch(void* const* d_in, const int* in_sizes, int n_in,
                              void* d_out, int out_size, void* d_ws, size_t ws_size,
                              hipStream_t stream)
{
    (void)in_sizes; (void)n_in; (void)out_size; (void)ws_size;
    const float* H0     = (const float*)d_in[0];
    const float* Hmid   = (const float*)d_in[1];
    const float* Hlast  = (const float*)d_in[2];
    const float* S0     = (const float*)d_in[3];
    const float* Smid   = (const float*)d_in[4];
    const float* Slast  = (const float*)d_in[5];
    const float* th0    = (const float*)d_in[6];
    const float* thmid  = (const float*)d_in[7];
    const float* thlast = (const float*)d_in[8];
    const float* precip = (const float*)d_in[9];
    float* out  = (float*)d_out;
    float* bufA = (float*)d_ws;        // inflow ping
    float* bufB = bufA + 1024;         // inflow pong

    layer0_kernel<<<1, 64, 0, stream>>>(H0, S0, th0, precip, out, bufA, bufB);

    float* cur = bufA;
    float* nxt = bufB;
    for (int l = 0; l < 14; ++l) {
        mid_kernel<<<256, 256, 0, stream>>>(Hmid + (size_t)l * 1024,
                                            Smid + (size_t)l * 1024 * 1024 * 2,
                                            thmid + (size_t)l * 1024 * 1024,
                                            cur, nxt,
                                            out + 1 + (size_t)l * 1024,
                                            precip);
        float* t = cur; cur = nxt; nxt = t;
    }

    last_kernel<<<4, 256, 0, stream>>>(Hlast, Slast, thlast, cur, out);
}

// Round 2
// 301.200 us; speedup vs baseline: 1.9715x; 1.9715x over previous
//
#include <hip/hip_runtime.h>
#include <math.h>

#define TWO_G 19.6f   // 2*9.8, matches jnp's folded 2.0*G constant
#define NPART 256     // partial-sum rows (== mid grid size)

__device__ __forceinline__ float flow_q(float th, float d, float a) {
    // matches reference association: (theta * sqrt(2*G*h)) * area
    return th * sqrtf(TWO_G * d) * a;
}

__device__ __forceinline__ float wave_sum(float v) {
#pragma unroll
    for (int o = 32; o > 0; o >>= 1) v += __shfl_xor(v, o);
    return v;
}

// ---------------- Layer 0: single head bucket, 1024 spigots. One wave. ----------------
// Writes q0[i] into P0[i] (row 0 of the partial buffer); first mid layer reads npart=1.
__global__ __launch_bounds__(64)
void layer0_kernel(const float* __restrict__ H0p, const float* __restrict__ S0,
                   const float* __restrict__ theta0, const float* __restrict__ precip,
                   float* __restrict__ out, float* __restrict__ P0)
{
    const int lane = threadIdx.x;
    const float H  = H0p[0];
    const float pl = precip[0] * 0.0625f;          // precip / 16 (exact)

    const float2* S2 = (const float2*)S0;
    float2 sv[16]; float tv[16];
#pragma unroll
    for (int c = 0; c < 16; ++c) { sv[c] = S2[c * 64 + lane]; tv[c] = theta0[c * 64 + lane]; }

    float h0 = __shfl(sv[0].x, 0);
    float a0 = __shfl(sv[0].y, 0);
    float t0 = __shfl(tv[0], 0);
    float d0 = (H + pl) - h0;
    float q0 = (d0 > 0.0f) ? flow_q(t0, d0, a0) : 0.0f;
    float cum = q0;
    float u   = H - 0.5f * cum;
    if (lane == 0) P0[0] = q0;

#pragma unroll
    for (int c = 0; c < 16; ++c) {
        int i = c * 64 + lane;
        float2 s = sv[c];
        unsigned long long avail = (c == 0) ? ~1ull : ~0ull;   // spigot 0 already done
        unsigned long long cand  = __ballot(s.x < u) & avail;
        float qmine = 0.0f;
        while (cand) {
            int j = __builtin_ctzll(cand);
            float hj = __shfl(s.x, j);
            float aj = __shfl(s.y, j);
            float tj = __shfl(tv[c], j);
            float d = u - hj;                    // > 0 by ballot
            float q = flow_q(tj, d, aj);
            cum += q;
            u = H - 0.5f * cum;
            if (lane == j) qmine = q;
            if (j >= 63) break;
            avail &= (~0ull << (j + 1));
            cand = __ballot(s.x < u) & avail;    // u decreased: subset of old cand
        }
        if (i > 0) P0[i] = qmine;
    }
    if (lane == 0) out[0] = (H - cum) + pl;      // H0_new
}

// ---------------- Mid layers: 1024 buckets, one wave per bucket, 4 buckets/block. ----
// Inflow gathered from npart partial rows of Pin; block-local LDS aggregation of q,
// dense partial row written to Pout[blockIdx]. No global atomics anywhere.
__global__ __launch_bounds__(256)
void mid_kernel(const float* __restrict__ Hl, const float* __restrict__ Sl,
                const float* __restrict__ thl, const float* __restrict__ Pin,
                int npart, float* __restrict__ Pout, float* __restrict__ outl,
                const float* __restrict__ precip)
{
    __shared__ float acc[1024];
    const int tid  = threadIdx.x;
    const int lane = tid & 63;
    const int b    = blockIdx.x * 4 + (tid >> 6);

#pragma unroll
    for (int r = 0; r < 4; ++r) acc[r * 256 + tid] = 0.0f;
    __syncthreads();

    const float pb = precip[0] * (0.0625f / 1024.0f);   // exact: 2^-14 * precip

    // gather this bucket's inflow partials (lane-parallel, then butterfly reduce)
    float part = 0.0f;
    for (int k = lane; k < npart; k += 64) part += Pin[k * 1024 + b];

    // prefetch the bucket's full S row and theta row into registers
    const float2* S2   = (const float2*)Sl + (size_t)b * 1024;
    const float*  thrw = thl + (size_t)b * 1024;
    float2 sv[16]; float tv[16];
#pragma unroll
    for (int c = 0; c < 16; ++c) { sv[c] = S2[c * 64 + lane]; tv[c] = thrw[c * 64 + lane]; }

    const float H      = Hl[b];
    const float inflow = pb + wave_sum(part);

    float h0 = __shfl(sv[0].x, 0);
    float a0 = __shfl(sv[0].y, 0);
    float t0 = __shfl(tv[0], 0);
    float d0 = (H + inflow) - h0;
    float q0 = (d0 > 0.0f) ? flow_q(t0, d0, a0) : 0.0f;
    float cum = q0;
    float u   = H - 0.5f * cum;
    if (lane == 0 && q0 != 0.0f) atomicAdd(&acc[0], q0);   // LDS, fire-and-forget

#pragma unroll
    for (int c = 0; c < 16; ++c) {
        float2 s = sv[c];
        unsigned long long avail = (c == 0) ? ~1ull : ~0ull;
        unsigned long long cand  = __ballot(s.x < u) & avail;
        float qmine = 0.0f;
        while (cand) {
            int j = __builtin_ctzll(cand);
            float hj = __shfl(s.x, j);
            float aj = __shfl(s.y, j);
            float tj = __shfl(tv[c], j);
            float d = u - hj;
            float q = flow_q(tj, d, aj);
            cum += q;
            u = H - 0.5f * cum;
            if (lane == j) qmine = q;
            if (j >= 63) break;
            avail &= (~0ull << (j + 1));
            cand = __ballot(s.x < u) & avail;
        }
        if (qmine != 0.0f) atomicAdd(&acc[c * 64 + lane], qmine);  // LDS
    }
    if (lane == 0) outl[b] = (H - cum) + inflow;          // H_mid_new[l][b]

    __syncthreads();
#pragma unroll
    for (int r = 0; r < 4; ++r)
        Pout[(size_t)blockIdx.x * 1024 + r * 256 + tid] = acc[r * 256 + tid];
}

// ---------------- Last layer: 1024 buckets, 1 spigot each; wave-per-bucket gather. ---
__global__ __launch_bounds__(256)
void last_kernel(const float* __restrict__ Hlast, const float* __restrict__ Slast,
                 const float* __restrict__ thlast, const float* __restrict__ Pin,
                 const float* __restrict__ precip, float* __restrict__ out)
{
    const int lane = threadIdx.x & 63;
    const int b    = blockIdx.x * 4 + (threadIdx.x >> 6);
    const float pb = precip[0] * (0.0625f / 1024.0f);

    float part = 0.0f;
#pragma unroll
    for (int k = 0; k < NPART / 64; ++k) part += Pin[(k * 64 + lane) * 1024 + b];
    float inflow = pb + wave_sum(part);

    if (lane == 0) {
        float H = Hlast[b];
        float2 s = ((const float2*)Slast)[b];
        float d = (H + inflow) - s.x;
        float q = (d > 0.0f) ? flow_q(thlast[b], d, s.y) : 0.0f;
        out[1 + 14 * 1024 + b]        = (H - q) + inflow;   // H_last_new
        out[1 + 14 * 1024 + 1024 + b] = q;                  // q_last
    }
}

extern "C" void kernel_launch(void* const* d_in, const int* in_sizes, int n_in,
                              void* d_out, int out_size, void* d_ws, size_t ws_size,
                              hipStream_t stream)
{
    (void)in_sizes; (void)n_in; (void)out_size; (void)ws_size;
    const float* H0     = (const float*)d_in[0];
    const float* Hmid   = (const float*)d_in[1];
    const float* Hlast  = (const float*)d_in[2];
    const float* S0     = (const float*)d_in[3];
    const float* Smid   = (const float*)d_in[4];
    const float* Slast  = (const float*)d_in[5];
    const float* th0    = (const float*)d_in[6];
    const float* thmid  = (const float*)d_in[7];
    const float* thlast = (const float*)d_in[8];
    const float* precip = (const float*)d_in[9];
    float* out = (float*)d_out;
    float* PA  = (float*)d_ws;                 // NPART x 1024 partials (ping)
    float* PB  = PA + (size_t)NPART * 1024;    // pong

    layer0_kernel<<<1, 64, 0, stream>>>(H0, S0, th0, precip, out, PA);

    float* cur = PA;
    float* nxt = PB;
    int npart = 1;                             // layer0 wrote a single partial row
    for (int l = 0; l < 14; ++l) {
        mid_kernel<<<256, 256, 0, stream>>>(Hmid + (size_t)l * 1024,
                                            Smid + (size_t)l * 1024 * 1024 * 2,
                                            thmid + (size_t)l * 1024 * 1024,
                                            cur, npart, nxt,
                                            out + 1 + (size_t)l * 1024,
                                            precip);
        float* t = cur; cur = nxt; nxt = t;
        npart = NPART;
    }

    last_kernel<<<256, 256, 0, stream>>>(Hlast, Slast, thlast, cur, precip, out);
}